// Round 12
// baseline (234.942 us; speedup 1.0000x reference)
//
#include <hip/hip_runtime.h>
#include <hip/hip_fp16.h>
#include <math.h>

#define NUM_CLASSES 10

// Bucketed CSR build parameters (128 nodes/bucket -> 782 buckets)
#define BSH 7
#define BSZ 128            // nodes per bucket
#define BCAP 1792          // max edges per bucket (mean ~1280, sigma ~36; +14 sigma)
#define NBMAX 1024         // static LDS histogram capacity
#define P1BATCH 4096       // edges per csr_p1 block (16/thread)

typedef _Float16 half8  __attribute__((ext_vector_type(8)));
typedef _Float16 half4t __attribute__((ext_vector_type(4)));
typedef float    floatx4 __attribute__((ext_vector_type(4)));

// ---------------------------------------------------------------------------
// prep: zero bucket_fill + fp16 transposes of W1,W2 (k-stride K+8) and the
// classifier Wl -> Wct[16 classes][136]. grid = 97 blocks.
// ---------------------------------------------------------------------------
__global__ __launch_bounds__(256) void prep_kernel(const float* __restrict__ W1,
                                                   const float* __restrict__ W2,
                                                   const float* __restrict__ Wlc,
                                                   _Float16* __restrict__ W1t,
                                                   _Float16* __restrict__ W2t,
                                                   _Float16* __restrict__ Wct,
                                                   int* __restrict__ fill, int nbuck) {
    const int b = blockIdx.x, tid = threadIdx.x;
    if (b == 0) {
        for (int i = tid; i < nbuck; i += 256) fill[i] = 0;
    }
    if (b < 32) {
        int i = b * 256 + tid;            // 8192 = 64*128
        int k = i >> 7, c = i & 127;
        W1t[c * 72 + k] = (_Float16)W1[i];
    } else if (b < 96) {
        int i = (b - 32) * 256 + tid;     // 16384 = 128*128
        int k = i >> 7, c = i & 127;
        W2t[c * 136 + k] = (_Float16)W2[i];
    } else {
        for (int i = tid; i < 16 * 136; i += 256) {
            int c = i / 136, k = i - c * 136;
            float v = (c < NUM_CLASSES && k < 128) ? Wlc[k * NUM_CLASSES + c] : 0.0f;
            Wct[i] = (_Float16)v;
        }
    }
}

// ---------------------------------------------------------------------------
// CSR pass 1 (R9-proven direct scatter, 12 KB LDS): partition edges into
// dst-range buckets with block-level reservations.
// ---------------------------------------------------------------------------
__global__ __launch_bounds__(256) void csr_p1_kernel(const int* __restrict__ src,
                                                     const int* __restrict__ dst,
                                                     int* __restrict__ bucket_fill,
                                                     unsigned* __restrict__ pairs, int E) {
    __shared__ int hist[NBMAX], base[NBMAX], cur[NBMAX];
    const int tid = threadIdx.x;
    for (int i = tid; i < NBMAX; i += 256) { hist[i] = 0; cur[i] = 0; }
    __syncthreads();
    const int bb = blockIdx.x * P1BATCH;
    unsigned pk[16];
    int bk[16];
    int cnt = 0;
#pragma unroll
    for (int i = 0; i < 16; ++i) {
        int idx = bb + i * 256 + tid;
        if (idx < E) {
            int s = src[idx], d = dst[idx];
            bk[i] = d >> BSH;
            pk[i] = ((unsigned)s << BSH) | (unsigned)(d & (BSZ - 1));
            atomicAdd(&hist[bk[i]], 1);
            cnt = i + 1;
        }
    }
    __syncthreads();
    for (int i = tid; i < NBMAX; i += 256)
        if (hist[i] > 0) base[i] = atomicAdd(&bucket_fill[i], hist[i]);
    __syncthreads();
#pragma unroll
    for (int i = 0; i < 16; ++i) {
        if (i < cnt) {
            int b = bk[i];
            int r = atomicAdd(&cur[b], 1) + base[b];
            if (r < BCAP) pairs[(size_t)b * BCAP + r] = pk[i];
        }
    }
}

// ---------------------------------------------------------------------------
// CSR pass 2: one block per bucket (782). Inline prefix over bucket_fill;
// LDS counters/scan/cursors; emits csr_src, rowstart[N+1], dinv, and
// prescaled fp16 features xs_h = dinv*x.
// ---------------------------------------------------------------------------
__global__ __launch_bounds__(256) void csr_p2_kernel(const int* __restrict__ bucket_fill,
                                                     const unsigned* __restrict__ pairs,
                                                     const float* __restrict__ x,
                                                     int* __restrict__ rowstart,
                                                     float* __restrict__ dinv,
                                                     int* __restrict__ csr_src,
                                                     __half2* __restrict__ xs_h,
                                                     int N, int nbuck) {
    __shared__ int cnt[BSZ], excl[BSZ], cur[BSZ];
    __shared__ int s1[256];
    const int tid = threadIdx.x;
    const int b = blockIdx.x;
    const int node0 = b << BSH;
    const int nodes_b = min(BSZ, N - node0);

    if (tid < BSZ) { cnt[tid] = 0; cur[tid] = 0; }
    int part = 0;
    for (int j = tid; j < b; j += 256) part += bucket_fill[j];
    s1[tid] = part;
    __syncthreads();
    for (int off = 128; off > 0; off >>= 1) {
        if (tid < off) s1[tid] += s1[tid + off];
        __syncthreads();
    }
    const int bbase = s1[0];
    const int ne = bucket_fill[b];
    __syncthreads();

    const unsigned* bp = pairs + (size_t)b * BCAP;
    for (int i = tid; i < ne; i += 256)
        atomicAdd(&cnt[bp[i] & (BSZ - 1)], 1);
    __syncthreads();
    int c = (tid < BSZ) ? cnt[tid] : 0;
    if (tid < BSZ) s1[tid] = c;
    __syncthreads();
    for (int off = 1; off < BSZ; off <<= 1) {
        int t = (tid < BSZ && tid >= off) ? s1[tid - off] : 0;
        __syncthreads();
        if (tid < BSZ) s1[tid] += t;
        __syncthreads();
    }
    if (tid < BSZ) excl[tid] = s1[tid] - c;
    __syncthreads();

    if (tid < nodes_b) {
        rowstart[node0 + tid] = bbase + excl[tid];
        dinv[node0 + tid] = rsqrtf((float)cnt[tid] + 1.0f);
    }
    if (b == nbuck - 1 && tid == 0) rowstart[N] = bbase + ne;

    for (int i = tid; i < nodes_b * 32; i += 256) {
        int ln = i >> 5;
        float d = rsqrtf((float)cnt[ln] + 1.0f);
        float2 v = ((const float2*)x)[(size_t)node0 * 32 + i];
        xs_h[(size_t)node0 * 32 + i] = __floats2half2_rn(v.x * d, v.y * d);
    }
    for (int i = tid; i < ne; i += 256) {
        unsigned p = bp[i];
        int d = (int)(p & (BSZ - 1));
        int r = atomicAdd(&cur[d], 1);
        csr_src[bbase + excl[d] + r] = (int)(p >> BSH);
    }
}

// ---------------------------------------------------------------------------
// Layer-1 aggregation, F=64, pair-packed: half-wave h handles edges 2u+h,
// feat f2 = lane&31 -> per-row loads issued once. shfl_xor(32) combine.
// ---------------------------------------------------------------------------
__global__ __launch_bounds__(256) void gather64_kernel(const __half2* __restrict__ xs,
                                                       const float* __restrict__ dinv,
                                                       const int* __restrict__ rowstart,
                                                       const int* __restrict__ csr_src,
                                                       __half2* __restrict__ out, int N) {
    int node = (blockIdx.x * 256 + threadIdx.x) >> 6;
    int lane = threadIdx.x & 63;
    if (node >= N) return;
    const int h = lane >> 5;
    const int f2 = lane & 31;

    int beg = rowstart[node];
    int end = rowstart[node + 1];
    int deg = end - beg;

    float2 self = __half22float2(xs[(size_t)node * 32 + f2]);
    float2 acc = make_float2(0.f, 0.f);

    if (deg <= 16) {
        int myidx = (lane < deg) ? csr_src[beg + lane] : node;
        if (h == 0) {
            float cmp = (float)(deg - 15);   // 1 (self) - (16-deg) pads
            acc.x = self.x * cmp;
            acc.y = self.y * cmp;
        }
        float2 v[8];
#pragma unroll
        for (int u = 0; u < 8; ++u) {
            int s = __shfl(myidx, 2 * u + h);
            v[u] = __half22float2(xs[(size_t)s * 32 + f2]);
        }
#pragma unroll
        for (int u = 0; u < 8; ++u) { acc.x += v[u].x; acc.y += v[u].y; }
    } else {
        int lim = deg < 64 ? deg : 64;
        int myidx = (lane < lim) ? csr_src[beg + lane] : node;
        int itersUp = (lim + 15) & ~15;
        if (h == 0) {
            float cmp = (float)(1 - (itersUp - lim));
            acc.x = self.x * cmp;
            acc.y = self.y * cmp;
        }
        for (int j = 0; j < itersUp; j += 16) {
            float2 v[8];
#pragma unroll
            for (int u = 0; u < 8; ++u) {
                int s = __shfl(myidx, j + 2 * u + h);
                v[u] = __half22float2(xs[(size_t)s * 32 + f2]);
            }
#pragma unroll
            for (int u = 0; u < 8; ++u) { acc.x += v[u].x; acc.y += v[u].y; }
        }
        if (h == 0) {
            for (int j = beg + 64; j < end; ++j) {   // rare: degree > 64
                float2 v = __half22float2(xs[(size_t)csr_src[j] * 32 + f2]);
                acc.x += v.x;
                acc.y += v.y;
            }
        }
    }
    acc.x += __shfl_xor(acc.x, 32);
    acc.y += __shfl_xor(acc.y, 32);
    if (lane < 32) {
        float d = dinv[node];
        out[(size_t)node * 32 + f2] = __floats2half2_rn(d * acc.x, d * acc.y);
    }
}

// ---------------------------------------------------------------------------
// Layer-2 aggregation, F=128, FEATURE-HALF PASS (hofs = 0 or 32 half2).
// Each pass touches only one 128B line per 256B row -> 12.8 MB working set
// per pass (vs 25.6 monolithic) -> higher L2 hit rate. Pair-packed like
// gather64; row stride 64 half2.
// ---------------------------------------------------------------------------
__global__ __launch_bounds__(256) void gather128h_kernel(const __half2* __restrict__ hs,
                                                         const float* __restrict__ dinv,
                                                         const int* __restrict__ rowstart,
                                                         const int* __restrict__ csr_src,
                                                         __half2* __restrict__ out,
                                                         int N, int hofs) {
    int node = (blockIdx.x * 256 + threadIdx.x) >> 6;
    int lane = threadIdx.x & 63;
    if (node >= N) return;
    const int h = lane >> 5;
    const int f2 = (lane & 31) + hofs;

    int beg = rowstart[node];
    int end = rowstart[node + 1];
    int deg = end - beg;

    float2 self = __half22float2(hs[(size_t)node * 64 + f2]);
    float2 acc = make_float2(0.f, 0.f);

    if (deg <= 16) {
        int myidx = (lane < deg) ? csr_src[beg + lane] : node;
        if (h == 0) {
            float cmp = (float)(deg - 15);
            acc.x = self.x * cmp;
            acc.y = self.y * cmp;
        }
        float2 v[8];
#pragma unroll
        for (int u = 0; u < 8; ++u) {
            int s = __shfl(myidx, 2 * u + h);
            v[u] = __half22float2(hs[(size_t)s * 64 + f2]);
        }
#pragma unroll
        for (int u = 0; u < 8; ++u) { acc.x += v[u].x; acc.y += v[u].y; }
    } else {
        int lim = deg < 64 ? deg : 64;
        int myidx = (lane < lim) ? csr_src[beg + lane] : node;
        int itersUp = (lim + 15) & ~15;
        if (h == 0) {
            float cmp = (float)(1 - (itersUp - lim));
            acc.x = self.x * cmp;
            acc.y = self.y * cmp;
        }
        for (int j = 0; j < itersUp; j += 16) {
            float2 v[8];
#pragma unroll
            for (int u = 0; u < 8; ++u) {
                int s = __shfl(myidx, j + 2 * u + h);
                v[u] = __half22float2(hs[(size_t)s * 64 + f2]);
            }
#pragma unroll
            for (int u = 0; u < 8; ++u) { acc.x += v[u].x; acc.y += v[u].y; }
        }
        if (h == 0) {
            for (int j = beg + 64; j < end; ++j) {
                float2 v = __half22float2(hs[(size_t)csr_src[j] * 64 + f2]);
                acc.x += v.x;
                acc.y += v.y;
            }
        }
    }
    acc.x += __shfl_xor(acc.x, 32);
    acc.y += __shfl_xor(acc.y, 32);
    if (lane < 32) {
        float d = dinv[node];
        out[(size_t)node * 64 + f2] = __floats2half2_rn(d * acc.x, d * acc.y);
    }
}

// ---------------------------------------------------------------------------
// MFMA GEMM + bias + ReLU (layer 1): Out = dinv*relu(In @ W + b), fp16 out.
// ---------------------------------------------------------------------------
template <int K, bool SCALE_OUT>
__global__ __launch_bounds__(256) void gemm_mfma_kernel(const _Float16* __restrict__ In,
                                                        const _Float16* __restrict__ Wt,
                                                        const float* __restrict__ bias,
                                                        const float* __restrict__ dinv,
                                                        _Float16* __restrict__ Out, int N) {
    constexpr int KP = K + 8;
    constexpr int NC = K / 32;
    __shared__ _Float16 Wl[128 * KP];
    __shared__ float bias_s[128];
    const int tid = threadIdx.x;

    for (int i = tid; i < (128 * KP) / 8; i += 256)
        ((floatx4*)Wl)[i] = ((const floatx4*)Wt)[i];
    if (tid < 128) bias_s[tid] = bias[tid];
    __syncthreads();

    const int lane = tid & 63;
    const int wave = tid >> 6;
    const int q = lane >> 4;
    const int l15 = lane & 15;

#pragma unroll
    for (int iter = 0; iter < 2; ++iter) {
        int myrow = blockIdx.x * 128 + iter * 64 + wave * 16 + l15;
        int r = myrow < N ? myrow : N - 1;
        half8 xf[NC];
#pragma unroll
        for (int c = 0; c < NC; ++c)
            xf[c] = *(const half8*)(In + (size_t)r * K + c * 32 + q * 8);
        floatx4 acc[8];
#pragma unroll
        for (int t = 0; t < 8; ++t) acc[t] = (floatx4){0.f, 0.f, 0.f, 0.f};
#pragma unroll
        for (int c = 0; c < NC; ++c) {
#pragma unroll
            for (int t = 0; t < 8; ++t) {
                half8 wf = *(const half8*)(Wl + (t * 16 + l15) * KP + c * 32 + q * 8);
                acc[t] = __builtin_amdgcn_mfma_f32_16x16x32_f16(wf, xf[c], acc[t], 0, 0, 0);
            }
        }
        if (myrow < N) {
            float sc = SCALE_OUT ? dinv[myrow] : 1.0f;
#pragma unroll
            for (int t = 0; t < 8; ++t) {
                int c0 = t * 16 + q * 4;
                floatx4 bv = *(const floatx4*)&bias_s[c0];
                half4t hh;
#pragma unroll
                for (int j = 0; j < 4; ++j)
                    hh[j] = (_Float16)(sc * fmaxf(acc[t][j] + bv[j], 0.0f));
                *(half4t*)(Out + (size_t)myrow * 128 + c0) = hh;
            }
        }
    }
}

// ---------------------------------------------------------------------------
// Layer 2 GEMM + ReLU + classifier + log_softmax, fused (R8-proven).
// ---------------------------------------------------------------------------
__global__ __launch_bounds__(256) void gemm_final_kernel(const _Float16* __restrict__ In,
                                                         const _Float16* __restrict__ Wt,
                                                         const float* __restrict__ bias,
                                                         const _Float16* __restrict__ Wct,
                                                         const float* __restrict__ bl,
                                                         float* __restrict__ out, int N) {
    constexpr int K = 128, KP = 136, NC = 4;
    __shared__ _Float16 Wl[128 * KP];
    __shared__ _Float16 Wc[16 * KP];
    __shared__ float bias_s[128];
    __shared__ float bl_s[16];
    __shared__ _Float16 act_s[4][16 * KP];
    const int tid = threadIdx.x;

    for (int i = tid; i < (128 * KP) / 8; i += 256)
        ((floatx4*)Wl)[i] = ((const floatx4*)Wt)[i];
    for (int i = tid; i < (16 * KP) / 8; i += 256)
        ((floatx4*)Wc)[i] = ((const floatx4*)Wct)[i];
    if (tid < 128) bias_s[tid] = bias[tid];
    if (tid < 16) bl_s[tid] = (tid < NUM_CLASSES) ? bl[tid] : -1e30f;
    __syncthreads();

    const int lane = tid & 63;
    const int wave = tid >> 6;
    const int q = lane >> 4;
    const int l15 = lane & 15;
    _Float16* As = act_s[wave];

    half8 wcf[NC];
#pragma unroll
    for (int c = 0; c < NC; ++c)
        wcf[c] = *(const half8*)(Wc + l15 * KP + c * 32 + q * 8);
    float myclsb[4];
#pragma unroll
    for (int reg = 0; reg < 4; ++reg) myclsb[reg] = bl_s[q * 4 + reg];

#pragma unroll
    for (int iter = 0; iter < 2; ++iter) {
        int myrow = blockIdx.x * 128 + iter * 64 + wave * 16 + l15;
        int r = myrow < N ? myrow : N - 1;
        half8 xf[NC];
#pragma unroll
        for (int c = 0; c < NC; ++c)
            xf[c] = *(const half8*)(In + (size_t)r * K + c * 32 + q * 8);
        floatx4 acc[8];
#pragma unroll
        for (int t = 0; t < 8; ++t) acc[t] = (floatx4){0.f, 0.f, 0.f, 0.f};
#pragma unroll
        for (int c = 0; c < NC; ++c) {
#pragma unroll
            for (int t = 0; t < 8; ++t) {
                half8 wf = *(const half8*)(Wl + (t * 16 + l15) * KP + c * 32 + q * 8);
                acc[t] = __builtin_amdgcn_mfma_f32_16x16x32_f16(wf, xf[c], acc[t], 0, 0, 0);
            }
        }
#pragma unroll
        for (int t = 0; t < 8; ++t) {
            int c0 = t * 16 + q * 4;
            floatx4 bv = *(const floatx4*)&bias_s[c0];
            half4t hh;
#pragma unroll
            for (int j = 0; j < 4; ++j)
                hh[j] = (_Float16)fmaxf(acc[t][j] + bv[j], 0.0f);
            *(half4t*)&As[l15 * KP + c0] = hh;
        }
        floatx4 lg = (floatx4){0.f, 0.f, 0.f, 0.f};
#pragma unroll
        for (int c = 0; c < NC; ++c) {
            half8 af = *(const half8*)(As + l15 * KP + c * 32 + q * 8);
            lg = __builtin_amdgcn_mfma_f32_16x16x32_f16(wcf[c], af, lg, 0, 0, 0);
        }
        if (myrow < N) {
            float v[4];
#pragma unroll
            for (int reg = 0; reg < 4; ++reg) v[reg] = lg[reg] + myclsb[reg];
            float mx = fmaxf(fmaxf(v[0], v[1]), fmaxf(v[2], v[3]));
            mx = fmaxf(mx, __shfl_xor(mx, 16));
            mx = fmaxf(mx, __shfl_xor(mx, 32));
            float sm = expf(v[0] - mx) + expf(v[1] - mx) + expf(v[2] - mx) + expf(v[3] - mx);
            sm += __shfl_xor(sm, 16);
            sm += __shfl_xor(sm, 32);
            float lse = mx + logf(sm);
#pragma unroll
            for (int reg = 0; reg < 4; ++reg) {
                int cls = q * 4 + reg;
                if (cls < NUM_CLASSES)
                    out[(size_t)myrow * NUM_CLASSES + cls] = v[reg] - lse;
            }
        }
    }
}

// ---------------------------------------------------------------------------
// Launch
// ---------------------------------------------------------------------------
extern "C" void kernel_launch(void* const* d_in, const int* in_sizes, int n_in,
                              void* d_out, int out_size, void* d_ws, size_t ws_size,
                              hipStream_t stream) {
    const float* x  = (const float*)d_in[0];
    const int*   ei = (const int*)d_in[1];
    const float* W1 = (const float*)d_in[2];
    const float* b1 = (const float*)d_in[3];
    const float* W2 = (const float*)d_in[4];
    const float* b2 = (const float*)d_in[5];
    const float* Wlc = (const float*)d_in[6];
    const float* bl = (const float*)d_in[7];
    float* out = (float*)d_out;

    const int N = in_sizes[0] / 64;         // 100000
    const int E = in_sizes[1] / 2;          // 1000000
    const int* src = ei;
    const int* dst = ei + E;
    const int nbuck = (N + BSZ - 1) >> BSH; // 782

    char* ws = (char*)d_ws;
    int*      bucket_fill = (int*)(ws + 0);              // 4 KB
    int*      rowstart    = (int*)(ws + 4096);           // ~400 KB
    float*    dinv        = (float*)(ws + 524288);       // 400 KB
    _Float16* W1t         = (_Float16*)(ws + 1048576);   // 18.4 KB
    _Float16* W2t         = (_Float16*)(ws + 1069056);   // 34.8 KB
    _Float16* Wct         = (_Float16*)(ws + 1103872);   // 4.4 KB
    unsigned* pairs       = (unsigned*)(ws + 2097152);   // 5.6 MB
    int*      csr_src     = (int*)(ws + 12582912);       // 4 MB
    __half2*  xs_h        = (__half2*)(ws + 16777216);   // 12.8 MB
    __half2*  g1h         = (__half2*)(ws + 33554432);   // 12.8 MB
    __half2*  g2h         = (__half2*)(ws + 46923776);   // 25.6 MB
    __half2*  a1_h        = (__half2*)(ws + 73400320);   // 25.6 MB

    const int P1B = (E + P1BATCH - 1) / P1BATCH;   // 245
    const int GB  = (N + 127) / 128;               // 782
    const int WVB = (N + 3) / 4;                   // 1 wave/node

    // --- CSR build front-end (R9-proven direct-scatter p1) ---
    prep_kernel<<<97, 256, 0, stream>>>(W1, W2, Wlc, W1t, W2t, Wct, bucket_fill, nbuck);
    csr_p1_kernel<<<P1B, 256, 0, stream>>>(src, dst, bucket_fill, pairs, E);
    csr_p2_kernel<<<nbuck, 256, 0, stream>>>(bucket_fill, pairs, x, rowstart, dinv,
                                             csr_src, xs_h, N, nbuck);

    // --- Layer 1: aggregate (64 feats, pair-packed) -> fp16, MFMA GEMM ---
    gather64_kernel<<<WVB, 256, 0, stream>>>(xs_h, dinv, rowstart, csr_src, g1h, N);
    gemm_mfma_kernel<64, true><<<GB, 256, 0, stream>>>((const _Float16*)g1h, W1t, b1, dinv,
                                                       (_Float16*)a1_h, N);

    // --- Layer 2: aggregate in two feature-half passes -> fused GEMM+cls ---
    gather128h_kernel<<<WVB, 256, 0, stream>>>(a1_h, dinv, rowstart, csr_src, g2h, N, 0);
    gather128h_kernel<<<WVB, 256, 0, stream>>>(a1_h, dinv, rowstart, csr_src, g2h, N, 32);
    gemm_final_kernel<<<GB, 256, 0, stream>>>((const _Float16*)g2h, W2t, b2, Wct, bl, out, N);
}

// Round 13
// 224.386 us; speedup vs baseline: 1.0470x; 1.0470x over previous
//
#include <hip/hip_runtime.h>
#include <hip/hip_fp16.h>
#include <math.h>

#define NUM_CLASSES 10

// Bucketed CSR build parameters (128 nodes/bucket -> 782 buckets)
#define BSH 7
#define BSZ 128            // nodes per bucket
#define BCAP 1792          // max edges per bucket (mean ~1280, sigma ~36; +14 sigma)
#define NBMAX 1024         // static LDS histogram capacity
#define P1BATCH 4096       // edges per p1-role block (16/thread)
#define PREPB 97           // prep-role blocks in the merged kernel

typedef _Float16 half8  __attribute__((ext_vector_type(8)));
typedef _Float16 half4t __attribute__((ext_vector_type(4)));
typedef float    floatx4 __attribute__((ext_vector_type(4)));

// ---------------------------------------------------------------------------
// Merged prep + CSR pass 1 (direct scatter, 12 KB LDS — the R9-proven body).
// Blocks 0..96: fp16 weight transposes. Blocks 97..: partition 4096 edges
// into dst-range buckets with block-level reservations.
// bucket_fill zeroed beforehand via hipMemsetAsync.
// ---------------------------------------------------------------------------
__global__ __launch_bounds__(256) void prep_p1_kernel(const float* __restrict__ W1,
                                                      const float* __restrict__ W2,
                                                      const float* __restrict__ Wlc,
                                                      _Float16* __restrict__ W1t,
                                                      _Float16* __restrict__ W2t,
                                                      _Float16* __restrict__ Wct,
                                                      const int* __restrict__ src,
                                                      const int* __restrict__ dst,
                                                      int* __restrict__ bucket_fill,
                                                      unsigned* __restrict__ pairs, int E) {
    __shared__ int hist[NBMAX], base[NBMAX], cur[NBMAX];   // 12 KB
    const int tid = threadIdx.x;
    const int b = blockIdx.x;

    if (b < PREPB) {
        if (b < 32) {
            int i = b * 256 + tid;            // 8192 = 64*128
            int k = i >> 7, c = i & 127;
            W1t[c * 72 + k] = (_Float16)W1[i];
        } else if (b < 96) {
            int i = (b - 32) * 256 + tid;     // 16384 = 128*128
            int k = i >> 7, c = i & 127;
            W2t[c * 136 + k] = (_Float16)W2[i];
        } else {
            for (int i = tid; i < 16 * 136; i += 256) {
                int c = i / 136, k = i - c * 136;
                float v = (c < NUM_CLASSES && k < 128) ? Wlc[k * NUM_CLASSES + c] : 0.0f;
                Wct[i] = (_Float16)v;
            }
        }
        return;
    }

    for (int i = tid; i < NBMAX; i += 256) { hist[i] = 0; cur[i] = 0; }
    __syncthreads();
    const int bb = (b - PREPB) * P1BATCH;
    unsigned pk[16];
    int bk[16];
    int cnt = 0;
#pragma unroll
    for (int i = 0; i < 16; ++i) {
        int idx = bb + i * 256 + tid;
        if (idx < E) {
            int s = src[idx], d = dst[idx];
            bk[i] = d >> BSH;
            pk[i] = ((unsigned)s << BSH) | (unsigned)(d & (BSZ - 1));
            atomicAdd(&hist[bk[i]], 1);
            cnt = i + 1;
        }
    }
    __syncthreads();
    for (int i = tid; i < NBMAX; i += 256)
        if (hist[i] > 0) base[i] = atomicAdd(&bucket_fill[i], hist[i]);
    __syncthreads();
#pragma unroll
    for (int i = 0; i < 16; ++i) {
        if (i < cnt) {
            int bi = bk[i];
            int r = atomicAdd(&cur[bi], 1) + base[bi];
            if (r < BCAP) pairs[(size_t)bi * BCAP + r] = pk[i];
        }
    }
}

// ---------------------------------------------------------------------------
// CSR pass 2: one block per bucket (782). Inline prefix over bucket_fill;
// LDS counters/scan/cursors; emits csr_src, rowstart[N+1], dinv, and
// prescaled fp16 features xs_h = dinv*x.
// ---------------------------------------------------------------------------
__global__ __launch_bounds__(256) void csr_p2_kernel(const int* __restrict__ bucket_fill,
                                                     const unsigned* __restrict__ pairs,
                                                     const float* __restrict__ x,
                                                     int* __restrict__ rowstart,
                                                     float* __restrict__ dinv,
                                                     int* __restrict__ csr_src,
                                                     __half2* __restrict__ xs_h,
                                                     int N, int nbuck) {
    __shared__ int cnt[BSZ], excl[BSZ], cur[BSZ];
    __shared__ int s1[256];
    const int tid = threadIdx.x;
    const int b = blockIdx.x;
    const int node0 = b << BSH;
    const int nodes_b = min(BSZ, N - node0);

    if (tid < BSZ) { cnt[tid] = 0; cur[tid] = 0; }
    int part = 0;
    for (int j = tid; j < b; j += 256) part += bucket_fill[j];
    s1[tid] = part;
    __syncthreads();
    for (int off = 128; off > 0; off >>= 1) {
        if (tid < off) s1[tid] += s1[tid + off];
        __syncthreads();
    }
    const int bbase = s1[0];
    const int ne = bucket_fill[b];
    __syncthreads();

    const unsigned* bp = pairs + (size_t)b * BCAP;
    for (int i = tid; i < ne; i += 256)
        atomicAdd(&cnt[bp[i] & (BSZ - 1)], 1);
    __syncthreads();
    int c = (tid < BSZ) ? cnt[tid] : 0;
    if (tid < BSZ) s1[tid] = c;
    __syncthreads();
    for (int off = 1; off < BSZ; off <<= 1) {
        int t = (tid < BSZ && tid >= off) ? s1[tid - off] : 0;
        __syncthreads();
        if (tid < BSZ) s1[tid] += t;
        __syncthreads();
    }
    if (tid < BSZ) excl[tid] = s1[tid] - c;
    __syncthreads();

    if (tid < nodes_b) {
        rowstart[node0 + tid] = bbase + excl[tid];
        dinv[node0 + tid] = rsqrtf((float)cnt[tid] + 1.0f);
    }
    if (b == nbuck - 1 && tid == 0) rowstart[N] = bbase + ne;

    for (int i = tid; i < nodes_b * 32; i += 256) {
        int ln = i >> 5;
        float d = rsqrtf((float)cnt[ln] + 1.0f);
        float2 v = ((const float2*)x)[(size_t)node0 * 32 + i];
        xs_h[(size_t)node0 * 32 + i] = __floats2half2_rn(v.x * d, v.y * d);
    }
    for (int i = tid; i < ne; i += 256) {
        unsigned p = bp[i];
        int d = (int)(p & (BSZ - 1));
        int r = atomicAdd(&cur[d], 1);
        csr_src[bbase + excl[d] + r] = (int)(p >> BSH);
    }
}

// ---------------------------------------------------------------------------
// Layer-1 aggregation F=64 (R9-best config: deg<=16 fast path, 16 loads in
// flight; lanes 32..63 mirror 0..31 via broadcast reads).
// ---------------------------------------------------------------------------
__global__ __launch_bounds__(256) void gather64_kernel(const __half2* __restrict__ xs,
                                                       const float* __restrict__ dinv,
                                                       const int* __restrict__ rowstart,
                                                       const int* __restrict__ csr_src,
                                                       __half2* __restrict__ out, int N) {
    int node = (blockIdx.x * 256 + threadIdx.x) >> 6;
    int lane = threadIdx.x & 63;
    if (node >= N) return;
    int f2 = lane & 31;

    int beg = rowstart[node];
    int end = rowstart[node + 1];
    int deg = end - beg;

    float2 self = __half22float2(xs[(size_t)node * 32 + f2]);
    float2 acc;

    if (deg <= 16) {
        int myidx = (lane < deg) ? csr_src[beg + lane] : node;
        float comp = (float)(deg - 15);      // 1 (self) - (16 - deg) pads
        acc.x = self.x * comp;
        acc.y = self.y * comp;
        float2 v[16];
#pragma unroll
        for (int u = 0; u < 16; ++u) {
            int s = __shfl(myidx, u);
            v[u] = __half22float2(xs[(size_t)s * 32 + f2]);
        }
#pragma unroll
        for (int u = 0; u < 16; ++u) { acc.x += v[u].x; acc.y += v[u].y; }
    } else {
        int lim = deg < 64 ? deg : 64;
        int myidx = (lane < lim) ? csr_src[beg + lane] : node;
        int itersUp = (lim + 7) & ~7;
        float comp = (float)(1 - (itersUp - lim));
        acc.x = self.x * comp;
        acc.y = self.y * comp;
        for (int j = 0; j < itersUp; j += 8) {
            int s[8];
#pragma unroll
            for (int u = 0; u < 8; ++u) s[u] = __shfl(myidx, j + u);
            float2 v[8];
#pragma unroll
            for (int u = 0; u < 8; ++u) v[u] = __half22float2(xs[(size_t)s[u] * 32 + f2]);
#pragma unroll
            for (int u = 0; u < 8; ++u) { acc.x += v[u].x; acc.y += v[u].y; }
        }
        for (int j = beg + 64; j < end; ++j) {
            float2 v = __half22float2(xs[(size_t)csr_src[j] * 32 + f2]);
            acc.x += v.x;
            acc.y += v.y;
        }
    }
    if (lane < 32) {
        float d = dinv[node];
        out[(size_t)node * 32 + f2] = __floats2half2_rn(d * acc.x, d * acc.y);
    }
}

// ---------------------------------------------------------------------------
// Layer-2 aggregation F=128 (R8-best config: plain 8-round unrolled loop).
// ---------------------------------------------------------------------------
__global__ __launch_bounds__(256) void gather128_kernel(const __half2* __restrict__ hs,
                                                        const float* __restrict__ dinv,
                                                        const int* __restrict__ rowstart,
                                                        const int* __restrict__ csr_src,
                                                        __half2* __restrict__ out, int N) {
    int node = (blockIdx.x * 256 + threadIdx.x) >> 6;
    int lane = threadIdx.x & 63;
    if (node >= N) return;

    int beg = rowstart[node];
    int end = rowstart[node + 1];
    int deg = end - beg;

    float2 self = __half22float2(hs[(size_t)node * 64 + lane]);
    int lim = deg < 64 ? deg : 64;
    int myidx = (lane < lim) ? csr_src[beg + lane] : node;
    int itersUp = (lim + 7) & ~7;
    float comp = (float)(1 - (itersUp - lim));
    float2 acc;
    acc.x = self.x * comp;
    acc.y = self.y * comp;

    for (int j = 0; j < itersUp; j += 8) {
        int s[8];
#pragma unroll
        for (int u = 0; u < 8; ++u) s[u] = __shfl(myidx, j + u);
        float2 v[8];
#pragma unroll
        for (int u = 0; u < 8; ++u) v[u] = __half22float2(hs[(size_t)s[u] * 64 + lane]);
#pragma unroll
        for (int u = 0; u < 8; ++u) { acc.x += v[u].x; acc.y += v[u].y; }
    }
    for (int j = beg + 64; j < end; ++j) {
        float2 v = __half22float2(hs[(size_t)csr_src[j] * 64 + lane]);
        acc.x += v.x;
        acc.y += v.y;
    }
    float d = dinv[node];
    out[(size_t)node * 64 + lane] = __floats2half2_rn(d * acc.x, d * acc.y);
}

// ---------------------------------------------------------------------------
// MFMA GEMM + bias + ReLU (layer 1): Out = dinv*relu(In @ W + b), fp16 out.
// ---------------------------------------------------------------------------
template <int K, bool SCALE_OUT>
__global__ __launch_bounds__(256) void gemm_mfma_kernel(const _Float16* __restrict__ In,
                                                        const _Float16* __restrict__ Wt,
                                                        const float* __restrict__ bias,
                                                        const float* __restrict__ dinv,
                                                        _Float16* __restrict__ Out, int N) {
    constexpr int KP = K + 8;
    constexpr int NC = K / 32;
    __shared__ _Float16 Wl[128 * KP];
    __shared__ float bias_s[128];
    const int tid = threadIdx.x;

    for (int i = tid; i < (128 * KP) / 8; i += 256)
        ((floatx4*)Wl)[i] = ((const floatx4*)Wt)[i];
    if (tid < 128) bias_s[tid] = bias[tid];
    __syncthreads();

    const int lane = tid & 63;
    const int wave = tid >> 6;
    const int q = lane >> 4;
    const int l15 = lane & 15;

#pragma unroll
    for (int iter = 0; iter < 2; ++iter) {
        int myrow = blockIdx.x * 128 + iter * 64 + wave * 16 + l15;
        int r = myrow < N ? myrow : N - 1;
        half8 xf[NC];
#pragma unroll
        for (int c = 0; c < NC; ++c)
            xf[c] = *(const half8*)(In + (size_t)r * K + c * 32 + q * 8);
        floatx4 acc[8];
#pragma unroll
        for (int t = 0; t < 8; ++t) acc[t] = (floatx4){0.f, 0.f, 0.f, 0.f};
#pragma unroll
        for (int c = 0; c < NC; ++c) {
#pragma unroll
            for (int t = 0; t < 8; ++t) {
                half8 wf = *(const half8*)(Wl + (t * 16 + l15) * KP + c * 32 + q * 8);
                acc[t] = __builtin_amdgcn_mfma_f32_16x16x32_f16(wf, xf[c], acc[t], 0, 0, 0);
            }
        }
        if (myrow < N) {
            float sc = SCALE_OUT ? dinv[myrow] : 1.0f;
#pragma unroll
            for (int t = 0; t < 8; ++t) {
                int c0 = t * 16 + q * 4;
                floatx4 bv = *(const floatx4*)&bias_s[c0];
                half4t hh;
#pragma unroll
                for (int j = 0; j < 4; ++j)
                    hh[j] = (_Float16)(sc * fmaxf(acc[t][j] + bv[j], 0.0f));
                *(half4t*)(Out + (size_t)myrow * 128 + c0) = hh;
            }
        }
    }
}

// ---------------------------------------------------------------------------
// Layer 2 GEMM + ReLU + classifier + log_softmax, fused (R8-proven).
// ---------------------------------------------------------------------------
__global__ __launch_bounds__(256) void gemm_final_kernel(const _Float16* __restrict__ In,
                                                         const _Float16* __restrict__ Wt,
                                                         const float* __restrict__ bias,
                                                         const _Float16* __restrict__ Wct,
                                                         const float* __restrict__ bl,
                                                         float* __restrict__ out, int N) {
    constexpr int K = 128, KP = 136, NC = 4;
    __shared__ _Float16 Wl[128 * KP];
    __shared__ _Float16 Wc[16 * KP];
    __shared__ float bias_s[128];
    __shared__ float bl_s[16];
    __shared__ _Float16 act_s[4][16 * KP];
    const int tid = threadIdx.x;

    for (int i = tid; i < (128 * KP) / 8; i += 256)
        ((floatx4*)Wl)[i] = ((const floatx4*)Wt)[i];
    for (int i = tid; i < (16 * KP) / 8; i += 256)
        ((floatx4*)Wc)[i] = ((const floatx4*)Wct)[i];
    if (tid < 128) bias_s[tid] = bias[tid];
    if (tid < 16) bl_s[tid] = (tid < NUM_CLASSES) ? bl[tid] : -1e30f;
    __syncthreads();

    const int lane = tid & 63;
    const int wave = tid >> 6;
    const int q = lane >> 4;
    const int l15 = lane & 15;
    _Float16* As = act_s[wave];

    half8 wcf[NC];
#pragma unroll
    for (int c = 0; c < NC; ++c)
        wcf[c] = *(const half8*)(Wc + l15 * KP + c * 32 + q * 8);
    float myclsb[4];
#pragma unroll
    for (int reg = 0; reg < 4; ++reg) myclsb[reg] = bl_s[q * 4 + reg];

#pragma unroll
    for (int iter = 0; iter < 2; ++iter) {
        int myrow = blockIdx.x * 128 + iter * 64 + wave * 16 + l15;
        int r = myrow < N ? myrow : N - 1;
        half8 xf[NC];
#pragma unroll
        for (int c = 0; c < NC; ++c)
            xf[c] = *(const half8*)(In + (size_t)r * K + c * 32 + q * 8);
        floatx4 acc[8];
#pragma unroll
        for (int t = 0; t < 8; ++t) acc[t] = (floatx4){0.f, 0.f, 0.f, 0.f};
#pragma unroll
        for (int c = 0; c < NC; ++c) {
#pragma unroll
            for (int t = 0; t < 8; ++t) {
                half8 wf = *(const half8*)(Wl + (t * 16 + l15) * KP + c * 32 + q * 8);
                acc[t] = __builtin_amdgcn_mfma_f32_16x16x32_f16(wf, xf[c], acc[t], 0, 0, 0);
            }
        }
#pragma unroll
        for (int t = 0; t < 8; ++t) {
            int c0 = t * 16 + q * 4;
            floatx4 bv = *(const floatx4*)&bias_s[c0];
            half4t hh;
#pragma unroll
            for (int j = 0; j < 4; ++j)
                hh[j] = (_Float16)fmaxf(acc[t][j] + bv[j], 0.0f);
            *(half4t*)&As[l15 * KP + c0] = hh;
        }
        floatx4 lg = (floatx4){0.f, 0.f, 0.f, 0.f};
#pragma unroll
        for (int c = 0; c < NC; ++c) {
            half8 af = *(const half8*)(As + l15 * KP + c * 32 + q * 8);
            lg = __builtin_amdgcn_mfma_f32_16x16x32_f16(wcf[c], af, lg, 0, 0, 0);
        }
        if (myrow < N) {
            float v[4];
#pragma unroll
            for (int reg = 0; reg < 4; ++reg) v[reg] = lg[reg] + myclsb[reg];
            float mx = fmaxf(fmaxf(v[0], v[1]), fmaxf(v[2], v[3]));
            mx = fmaxf(mx, __shfl_xor(mx, 16));
            mx = fmaxf(mx, __shfl_xor(mx, 32));
            float sm = expf(v[0] - mx) + expf(v[1] - mx) + expf(v[2] - mx) + expf(v[3] - mx);
            sm += __shfl_xor(sm, 16);
            sm += __shfl_xor(sm, 32);
            float lse = mx + logf(sm);
#pragma unroll
            for (int reg = 0; reg < 4; ++reg) {
                int cls = q * 4 + reg;
                if (cls < NUM_CLASSES)
                    out[(size_t)myrow * NUM_CLASSES + cls] = v[reg] - lse;
            }
        }
    }
}

// ---------------------------------------------------------------------------
// Launch
// ---------------------------------------------------------------------------
extern "C" void kernel_launch(void* const* d_in, const int* in_sizes, int n_in,
                              void* d_out, int out_size, void* d_ws, size_t ws_size,
                              hipStream_t stream) {
    const float* x  = (const float*)d_in[0];
    const int*   ei = (const int*)d_in[1];
    const float* W1 = (const float*)d_in[2];
    const float* b1 = (const float*)d_in[3];
    const float* W2 = (const float*)d_in[4];
    const float* b2 = (const float*)d_in[5];
    const float* Wlc = (const float*)d_in[6];
    const float* bl = (const float*)d_in[7];
    float* out = (float*)d_out;

    const int N = in_sizes[0] / 64;         // 100000
    const int E = in_sizes[1] / 2;          // 1000000
    const int* src = ei;
    const int* dst = ei + E;
    const int nbuck = (N + BSZ - 1) >> BSH; // 782

    char* ws = (char*)d_ws;
    int*      bucket_fill = (int*)(ws + 0);              // 4 KB
    int*      rowstart    = (int*)(ws + 4096);           // ~400 KB
    float*    dinv        = (float*)(ws + 524288);       // 400 KB
    _Float16* W1t         = (_Float16*)(ws + 1048576);   // 18.4 KB
    _Float16* W2t         = (_Float16*)(ws + 1069056);   // 34.8 KB
    _Float16* Wct         = (_Float16*)(ws + 1103872);   // 4.4 KB
    unsigned* pairs       = (unsigned*)(ws + 2097152);   // 5.6 MB
    int*      csr_src     = (int*)(ws + 12582912);       // 4 MB
    __half2*  xs_h        = (__half2*)(ws + 16777216);   // 12.8 MB
    __half2*  g1h         = (__half2*)(ws + 33554432);   // 12.8 MB
    __half2*  g2h         = (__half2*)(ws + 46923776);   // 25.6 MB
    __half2*  a1_h        = (__half2*)(ws + 73400320);   // 25.6 MB

    const int P1B = (E + P1BATCH - 1) / P1BATCH;   // 245
    const int GB  = (N + 127) / 128;               // 782
    const int WVB = (N + 3) / 4;                   // 1 wave/node

    // --- CSR build front-end (merged prep + direct-scatter p1) ---
    hipMemsetAsync(bucket_fill, 0, nbuck * sizeof(int), stream);
    prep_p1_kernel<<<PREPB + P1B, 256, 0, stream>>>(W1, W2, Wlc, W1t, W2t, Wct,
                                                    src, dst, bucket_fill, pairs, E);
    csr_p2_kernel<<<nbuck, 256, 0, stream>>>(bucket_fill, pairs, x, rowstart, dinv,
                                             csr_src, xs_h, N, nbuck);

    // --- Layer 1: aggregate (64 feats) -> fp16, MFMA GEMM ---
    gather64_kernel<<<WVB, 256, 0, stream>>>(xs_h, dinv, rowstart, csr_src, g1h, N);
    gemm_mfma_kernel<64, true><<<GB, 256, 0, stream>>>((const _Float16*)g1h, W1t, b1, dinv,
                                                       (_Float16*)a1_h, N);

    // --- Layer 2: aggregate (128 feats) -> fp16, fused GEMM+classifier+softmax ---
    gather128_kernel<<<WVB, 256, 0, stream>>>(a1_h, dinv, rowstart, csr_src, g2h, N);
    gemm_final_kernel<<<GB, 256, 0, stream>>>((const _Float16*)g2h, W2t, b2, Wct, bl, out, N);
}